// Round 14
// baseline (188.121 us; speedup 1.0000x reference)
//
#include <hip/hip_runtime.h>

// ---------------------------------------------------------------------------
// MaskedAutoregressiveFlow (RealNVP coupling) fused kernel for gfx950. R27.
// B=16384 rows, F=64, CTX=128, HID=512, L=8 layers, NB=2 hidden blocks.
//
// R27 = R26 fixed: v_pk_max_f32 DOES NOT EXIST on gfx950 (VOP3P f32 pack =
//       fma/add/mul only; R26 compile failed on it). Keep v_pk_fma_f32
//       (valid) for scale+bias (2 f32/instr, halves the 64 fma/thread/stage)
//       and do relu with scalar fmaxf (v_max_f32) as R25 did.
// Base = R25 (flow 106.2us: full-MX fp8 GEMMs, write-coalesced LDS layout,
// raw barriers, cross-stage B prefetch, composed perms, fused G3 coupling,
// coalesced pack). Per-element math identical (fused mul-add, max) ->
// absmax bit-identical. Everything else unchanged.
// C^T mapping (m101, dtype-indep): 32x32: m = lane&31,
// n = (reg&3)+8*(reg>>2)+4*(lane>>5); 16x16: m = lane&15, n = ntb*16+quad*4+reg.
// LDS layout (PACKED): pos(c) = ((c>>2)&1)*HALF + (c>>5)*16 + ((c>>3)&3)*4
// + (c&3); k-order sigma baked into the weight pack (k(g,j) = (g&1)*16 +
// (j>>2)*8 + ((g>>1)&1)*4 + (j&3)).
// ---------------------------------------------------------------------------

typedef float v2f  __attribute__((ext_vector_type(2)));
typedef float v4f  __attribute__((ext_vector_type(4)));
typedef float v16f __attribute__((ext_vector_type(16)));
typedef int   v4i  __attribute__((ext_vector_type(4)));
typedef int   v8i  __attribute__((ext_vector_type(8)));
typedef unsigned char uchar;
typedef unsigned long long ull;

#define BATCH 16384
#define NF    64
#define NCTX  128
#define NL    8

#define RS     528   // h row stride (bytes)
#define HHALF  256   // byte offset of high half-region (hbuf)
#define AST    208   // abuf row stride (bytes), K padded to 192
#define AHALF  96    // abuf half-region offset (K=192)

#define WSCALE     16.0f
#define WSCALE_INV 0.0625f

// packed-weight offsets (fp8 elements = bytes). W_in K padded 160->192.
#define WIN_EPL   (192 * 512)
#define WH_EPB    (512 * 512)
#define WOUT_EPL  (512 * 64)
#define OFF_WIN   ((size_t)0)
#define OFF_WH    ((size_t)(8 * WIN_EPL))
#define OFF_WOUT  (OFF_WH + (size_t)(16 * WH_EPB))
#define TOT_PACK_ELEMS (OFF_WOUT + (size_t)(8 * WOUT_EPL))
#define NEED_WS   (TOT_PACK_ELEMS)

// pack wave-unit counts
#define NU_IN   192    // 8 layers x 3 kb x 2 khalf x 4 g
#define NU_H    1024   // 16 mats  x 8 kb x 2 khalf x 4 g
#define NU_OUT  128    // 8 layers x 16 kc
#define NU_TOT  (NU_IN + NU_H + NU_OUT)   // 1344 waves

template<bool HI>
__device__ __forceinline__ unsigned int pk2(float a, float b, unsigned int old) {
    return __builtin_amdgcn_cvt_pk_fp8_f32(a, b, old, HI);
}
__device__ __forceinline__ uchar q8(float v) {
    return (uchar)(__builtin_amdgcn_cvt_pk_fp8_f32(v, v, 0u, false) & 0xffu);
}

// VOP3P packed dual-FP32 FMA (exists on gfx950; pk_max_f32 does NOT).
__device__ __forceinline__ v2f pk_fma(v2f a, v2f b, v2f c) {
    v2f d;
    asm("v_pk_fma_f32 %0, %1, %2, %3" : "=v"(d) : "v"(a), "v"(b), "v"(c));
    return d;
}

// Raw barrier: LDS-complete + s_barrier, NO vmcnt drain (global prefetches
// stay in flight). All inter-wave deps in flow_kernel are LDS-only.
__device__ __forceinline__ void bar_lds() {
    asm volatile("s_waitcnt lgkmcnt(0)" ::: "memory");
    __builtin_amdgcn_s_barrier();
    asm volatile("" ::: "memory");
}

// within-32 k base for pack group g: bytes [g*8, g*8+8) of a 32B lane frag
// hold k = kq(g) + (j>>2)*8 + (j&3), kq(g) = (g&1)*16 + ((g>>1)&1)*4.
__device__ __forceinline__ int kqg(int g) {
    return (g & 1) * 16 + ((g >> 1) & 1) * 4;
}

// ---------------------------------------------------------------------------
// pack: wave-per-unit, coalesced reads, register 8x8 transpose. (R25)
// ---------------------------------------------------------------------------
__global__ __launch_bounds__(256) void pack_weights_kernel(
    const float* __restrict__ W_in,
    const float* __restrict__ W_h,
    const float* __restrict__ W_out,
    unsigned char* __restrict__ ws) {
    const int wid  = (blockIdx.x * blockDim.x + threadIdx.x) >> 6;
    const int lane = threadIdx.x & 63;
    if (wid >= NU_TOT) return;

    if (wid < NU_IN + NU_H) {
        const float* src;
        uchar* dstbase;
        int kb, khalf, g, rawK;
        if (wid < NU_IN) {
            int i = wid / 24, r = wid % 24;           // layer, unit-in-layer
            kb = r >> 3; khalf = (r >> 2) & 1; g = r & 3;
            src = W_in + (size_t)i * (160 * 512); rawK = 160;
            dstbase = ws + OFF_WIN + (size_t)i * WIN_EPL + kb * 32768;
        } else {
            int u = wid - NU_IN;
            int ij = u >> 6, r = u & 63;              // matrix, unit-in-matrix
            kb = r >> 3; khalf = (r >> 2) & 1; g = r & 3;
            src = W_h + (size_t)ij * WH_EPB; rawK = 512;
            dstbase = ws + OFF_WH + (size_t)ij * WH_EPB + kb * 32768;
        }
        const int kbase = kb * 64 + khalf * 32;
        const int kq    = kqg(g);
        const int n0    = lane * 8;
        float v[8][8];
        if (kbase < rawK) {
#pragma unroll
            for (int j = 0; j < 8; ++j) {
                const int kj = kbase + kq + (j >> 2) * 8 + (j & 3);
                const float* p = src + (size_t)kj * 512 + n0;
                float4 a = ((const float4*)p)[0];
                float4 b = ((const float4*)p)[1];
                v[j][0] = a.x * WSCALE; v[j][1] = a.y * WSCALE;
                v[j][2] = a.z * WSCALE; v[j][3] = a.w * WSCALE;
                v[j][4] = b.x * WSCALE; v[j][5] = b.y * WSCALE;
                v[j][6] = b.z * WSCALE; v[j][7] = b.w * WSCALE;
            }
        } else {
#pragma unroll
            for (int j = 0; j < 8; ++j)
#pragma unroll
                for (int nn = 0; nn < 8; ++nn) v[j][nn] = 0.f;
        }
        // dest for nn=0; consecutive nn adds 32B
        uchar* dst = dstbase +
            ((lane >> 2) * 64 + 32 * khalf + (lane & 3) * 8) * 32 + g * 8;
#pragma unroll
        for (int nn = 0; nn < 8; ++nn) {
            uint2 o;
            o.x = pk2<false>(v[0][nn], v[1][nn], 0u);
            o.x = pk2<true >(v[2][nn], v[3][nn], o.x);
            o.y = pk2<false>(v[4][nn], v[5][nn], 0u);
            o.y = pk2<true >(v[6][nn], v[7][nn], o.y);
            *(uint2*)(dst + nn * 32) = o;
        }
    } else {
        int u = wid - (NU_IN + NU_H);
        int i = u >> 4, kc = u & 15;                  // layer, kc (32-k slab)
        const int n = lane;
        const float* src = W_out + (size_t)i * WOUT_EPL;
        float v[32];
#pragma unroll
        for (int k = 0; k < 32; ++k)
            v[k] = src[(size_t)(kc * 32 + k) * 64 + n] * WSCALE;
        uchar* dst = ws + OFF_WOUT + (size_t)i * 32768 +
                     (size_t)(kc >> 2) * 8192 + (size_t)(n >> 4) * 2048 +
                     (size_t)((((kc & 3) << 4) | (n & 15)) * 32);
#pragma unroll
        for (int g = 0; g < 4; ++g) {
            const int kq = kqg(g);
            uint2 o;
            o.x = pk2<false>(v[kq + 0], v[kq + 1], 0u);
            o.x = pk2<true >(v[kq + 2], v[kq + 3], o.x);
            o.y = pk2<false>(v[kq + 8], v[kq + 9], 0u);
            o.y = pk2<true >(v[kq + 10], v[kq + 11], o.y);
            *(uint2*)(dst + g * 8) = o;
        }
    }
}

__device__ __forceinline__ v16f mfma32(ull a, ull b, v16f c) {
    return __builtin_amdgcn_mfma_f32_32x32x16_fp8_fp8((long)a, (long)b, c, 0, 0, 0);
}
__device__ __forceinline__ v4f mfma16(ull a, ull b, v4f c) {
    return __builtin_amdgcn_mfma_f32_16x16x32_fp8_fp8((long)a, (long)b, c, 0, 0, 0);
}
// MX, both operands fp8 e4m3 (cbsz=0, blgp=0), scales = 1.0 (E8M0 127).
__device__ __forceinline__ v16f mfma64(v8i a, v8i b, v16f c) {
    return __builtin_amdgcn_mfma_scale_f32_32x32x64_f8f6f4(
        a, b, c, 0, 0, 0, 0x7f7f7f7f, 0, 0x7f7f7f7f);
}
__device__ __forceinline__ v4f mfma128(v8i a, v8i b, v4f c) {
    return __builtin_amdgcn_mfma_scale_f32_16x16x128_f8f6f4(
        a, b, c, 0, 0, 0, 0x7f7f7f7f, 0, 0x7f7f7f7f);
}

__device__ __forceinline__ v8i ldv8(const uchar* p) {
    v4i lo = *(const v4i*)p;
    v4i hi = *(const v4i*)(p + 16);
    return __builtin_shufflevector(lo, hi, 0, 1, 2, 3, 4, 5, 6, 7);
}

// B prefetch payloads (issued before the barrier preceding each stage)
struct BPre  { v8i b00, b10, b01, b11; };             // gemm32mx kb=0,1
struct BPre16 { v8i u0, v0, u1, v1; };                // gemm16 kb128=0,1 x 2 chains

__device__ __forceinline__ BPre prefB(const uchar* __restrict__ wpk,
                                      int pair, int lane) {
    const uchar* bp = wpk + (size_t)(pair * 128 + lane) * 32;
    BPre r;
    r.b00 = ldv8(bp);
    r.b10 = ldv8(bp + 2048);
    r.b01 = ldv8(bp + 32768);
    r.b11 = ldv8(bp + 32768 + 2048);
    return r;
}
__device__ __forceinline__ BPre16 prefB16(const uchar* __restrict__ wpk,
                                          int w, int lane) {
    const int npair = w & 1;
    const uchar* b0 = wpk + (size_t)npair * 2048 + (size_t)lane * 32;
    const uchar* b1 = wpk + (size_t)(npair + 2) * 2048 + (size_t)lane * 32;
    BPre16 r;
    r.u0 = ldv8(b0);        r.v0 = ldv8(b1);
    r.u1 = ldv8(b0 + 8192); r.v1 = ldv8(b1 + 8192);
    return r;
}

// ---------------------------------------------------------------------------
// MX 32x32x64 fp8 stage, 8-wave: wave owns strips {2p, 2p+1} x both m-tiles
// (4 v16f accs). SWAPPED operands (src0 = weight frag, src1 = act frag).
// D=2 B pipeline (kb=0,1 from caller's pre-barrier prefetch), A ping-pong.
// R27 epilogue: v_pk_fma_f32 (2 f32/instr) for scale+bias, scalar fmaxf
// relu; one ds_write_b128 per (strip, mhalf) as R25.
// ---------------------------------------------------------------------------
template<int NKB>
__device__ __forceinline__ void gemm32mx(
    const uchar* __restrict__ wpk,
    const float* __restrict__ bias,
    const uchar* __restrict__ Abuf, int ast, int halfoff,
    uchar* __restrict__ Obuf,
    int pair, int lane, BPre pre)
{
    const int l31 = lane & 31, hl = lane >> 5;
    v16f a00, a01, a10, a11;          // acc[strip][mhalf]
#pragma unroll
    for (int r = 0; r < 16; ++r) { a00[r] = 0.f; a01[r] = 0.f;
                                   a10[r] = 0.f; a11[r] = 0.f; }
    const uchar* aLo0 = Abuf + l31 * ast + hl * 16;   // rows 0..31, low region
    const uchar* aHi0 = aLo0 + halfoff;               // high region
    const uchar* aLo1 = aLo0 + 32 * ast;              // rows 32..63
    const uchar* aHi1 = aHi0 + 32 * ast;
    const uchar* bp = wpk + (size_t)(pair * 128 + lane) * 32;  // strip 2p base

    auto loadB = [&](int s, int kb) -> v8i {
        if (kb >= NKB) kb = NKB - 1;                  // clamped dup, in-bounds
        return ldv8(bp + s * 2048 + (size_t)kb * 32768);
    };
    auto loadA = [&](const uchar* lo_, const uchar* hi_, int kb) -> v8i {
        if (kb >= NKB) kb = NKB - 1;                  // clamped dup, in-bounds
        v4i lo = *(const v4i*)(lo_ + kb * 32);
        v4i hi = *(const v4i*)(hi_ + kb * 32);
        return __builtin_shufflevector(lo, hi, 0, 1, 2, 3, 4, 5, 6, 7);
    };

    // prologue: A for kb=0 (slot A) and kb=1 (slot B); B from prefetch
    v8i xA0 = loadA(aLo0, aHi0, 0), xA1 = loadA(aLo1, aHi1, 0);
    v8i xB0 = loadA(aLo0, aHi0, 1), xB1 = loadA(aLo1, aHi1, 1);
    v8i b00 = pre.b00, b10 = pre.b10;
    v8i b01 = pre.b01, b11 = pre.b11;
#pragma unroll 1
    for (int kb = 0; kb + 1 < NKB; kb += 2) {
        // compute kb (slot A), then refill slot A with kb+2
        a00 = mfma64(b00, xA0, a00);
        a01 = mfma64(b00, xA1, a01);
        a10 = mfma64(b10, xA0, a10);
        a11 = mfma64(b10, xA1, a11);
        xA0 = loadA(aLo0, aHi0, kb + 2);
        xA1 = loadA(aLo1, aHi1, kb + 2);
        b00 = loadB(0, kb + 2);
        b10 = loadB(1, kb + 2);
        // compute kb+1 (slot B), then refill slot B with kb+3
        a00 = mfma64(b01, xB0, a00);
        a01 = mfma64(b01, xB1, a01);
        a10 = mfma64(b11, xB0, a10);
        a11 = mfma64(b11, xB1, a11);
        xB0 = loadA(aLo0, aHi0, kb + 3);
        xB1 = loadA(aLo1, aHi1, kb + 3);
        b01 = loadB(0, kb + 3);
        b11 = loadB(1, kb + 3);
    }
    if constexpr (NKB & 1) {                          // tail kb = NKB-1 in slot A
        a00 = mfma64(b00, xA0, a00);
        a01 = mfma64(b00, xA1, a01);
        a10 = mfma64(b10, xA0, a10);
        a11 = mfma64(b10, xA1, a11);
    }

    // epilogue (C^T): lane = batch row m = l31 (mhalf0) / l31+32 (mhalf1);
    // reg-quad q of strip s covers n = s*32 + q*8 + 4*hl + {0..3} -> byte
    // pos (region hl) = s*16 + q*4 + {0..3}: ONE b128 per (strip, mhalf).
    // pk_fma for scale+bias (2 f32/instr); scalar fmaxf relu.
    const uchar* ob0 = Obuf + l31 * RS + hl * HHALF;  // mhalf 0
    const uchar* ob1 = ob0 + 32 * RS;                 // mhalf 1
    const v2f kinv = {WSCALE_INV, WSCALE_INV};
    auto emit = [&](const v16f& am0, const v16f& am1, int strip) {
        v4i w0, w1;
#pragma unroll
        for (int q = 0; q < 4; ++q) {
            const int n0 = strip * 32 + q * 8 + 4 * hl;
            float4 bv = *(const float4*)(bias + n0);
            const v2f blo = {bv.x, bv.y}, bhi = {bv.z, bv.w};
            v2f p0 = {am0[4 * q + 0], am0[4 * q + 1]};
            v2f p1 = {am0[4 * q + 2], am0[4 * q + 3]};
            v2f p2 = {am1[4 * q + 0], am1[4 * q + 1]};
            v2f p3 = {am1[4 * q + 2], am1[4 * q + 3]};
            p0 = pk_fma(p0, kinv, blo);
            p1 = pk_fma(p1, kinv, bhi);
            p2 = pk_fma(p2, kinv, blo);
            p3 = pk_fma(p3, kinv, bhi);
            unsigned int u0, u1;
            u0 = pk2<false>(fmaxf(p0[0], 0.f), fmaxf(p0[1], 0.f), 0u);
            u0 = pk2<true >(fmaxf(p1[0], 0.f), fmaxf(p1[1], 0.f), u0);
            u1 = pk2<false>(fmaxf(p2[0], 0.f), fmaxf(p2[1], 0.f), 0u);
            u1 = pk2<true >(fmaxf(p3[0], 0.f), fmaxf(p3[1], 0.f), u1);
            w0[q] = (int)u0;
            w1[q] = (int)u1;
        }
        *(v4i*)(ob0 + strip * 16) = w0;
        *(v4i*)(ob1 + strip * 16) = w1;
    };
    emit(a00, a01, pair * 2 + 0);
    emit(a10, a11, pair * 2 + 1);
}

// ---------------------------------------------------------------------------
// Non-packed fallback: 32x32x16 fp8 stage (pk on the fly, OLD layout:
// pos(c) = ((c>>3)&1)*HALF + (c>>4)*8 + (c&7)) — correctness path only.
// ---------------------------------------------------------------------------
template<int KC>
__device__ __forceinline__ void gemm32_raw(
    const float* __restrict__ wraw,    // raw fp32 [K][512]
    const float* __restrict__ bias,
    const uchar* __restrict__ Abuf, int ast, int ahalf,
    uchar* __restrict__ Obuf,
    int strip, int lane)
{
    constexpr int P = KC / 2;
    const int l31 = lane & 31, hl = lane >> 5;
    v16f acc0, acc1;
#pragma unroll
    for (int r = 0; r < 16; ++r) { acc0[r] = 0.f; acc1[r] = 0.f; }
    const uchar* a0p = Abuf + l31 * ast + hl * ahalf;   // rows 0..31
    const uchar* a1p = a0p + 32 * ast;                  // rows 32..63

    auto loadB = [&](int kc) -> ull {
        if (kc >= KC) kc = KC - 1;
        int n  = strip * 32 + l31;
        int k0 = kc * 16 + hl * 8;
        unsigned int lo, hi;
        lo = pk2<false>(wraw[(size_t)(k0 + 0) * 512 + n] * WSCALE,
                        wraw[(size_t)(k0 + 1) * 512 + n] * WSCALE, 0u);
        lo = pk2<true >(wraw[(size_t)(k0 + 2) * 512 + n] * WSCALE,
                        wraw[(size_t)(k0 + 3) * 512 + n] * WSCALE, lo);
        hi = pk2<false>(wraw[(size_t)(k0 + 4) * 512 + n] * WSCALE,
                        wraw[(size_t)(k0 + 5) * 512 + n] * WSCALE, 0u);
        hi = pk2<true >(wraw[(size_t)(k0 + 6) * 512 + n] * WSCALE,
                        wraw[(size_t)(k0 + 7) * 512 + n] * WSCALE, hi);
        return ((ull)hi << 32) | (ull)lo;
    };

    ull b0 = loadB(0), b1 = loadB(1), b2 = loadB(2), b3 = loadB(3);
    int p2 = 0;
#pragma unroll 1
    for (; p2 + 1 < P; p2 += 2) {
        ulonglong2 Aa0 = *(const ulonglong2*)(a0p + p2 * 16);
        ulonglong2 Aa1 = *(const ulonglong2*)(a1p + p2 * 16);
        acc0 = mfma32(Aa0.x, b0, acc0);
        acc1 = mfma32(Aa1.x, b0, acc1);
        b0 = loadB(2 * p2 + 4);
        acc0 = mfma32(Aa0.y, b1, acc0);
        acc1 = mfma32(Aa1.y, b1, acc1);
        b1 = loadB(2 * p2 + 5);
        ulonglong2 Ab0 = *(const ulonglong2*)(a0p + p2 * 16 + 16);
        ulonglong2 Ab1 = *(const ulonglong2*)(a1p + p2 * 16 + 16);
        acc0 = mfma32(Ab0.x, b2, acc0);
        acc1 = mfma32(Ab1.x, b2, acc1);
        b2 = loadB(2 * p2 + 6);
        acc0 = mfma32(Ab0.y, b3, acc0);
        acc1 = mfma32(Ab1.y, b3, acc1);
        b3 = loadB(2 * p2 + 7);
    }
    if constexpr (P & 1) {
        ulonglong2 Aa0 = *(const ulonglong2*)(a0p + (P - 1) * 16);
        ulonglong2 Aa1 = *(const ulonglong2*)(a1p + (P - 1) * 16);
        acc0 = mfma32(Aa0.x, b0, acc0);
        acc1 = mfma32(Aa1.x, b0, acc1);
        acc0 = mfma32(Aa0.y, b1, acc0);
        acc1 = mfma32(Aa1.y, b1, acc1);
    }

    const int n = strip * 32 + l31;
    const int nb = ((n >> 3) & 1) * HHALF + ((n >> 4) << 3) + (n & 7);
    const float bv = bias[n];
#pragma unroll
    for (int reg = 0; reg < 16; ++reg) {
        int row = (reg & 3) + 8 * (reg >> 2) + 4 * hl;
        float v0 = fmaxf(fmaf(acc0[reg], WSCALE_INV, bv), 0.f);
        Obuf[row * RS + nb] = q8(v0);
        float v1 = fmaxf(fmaf(acc1[reg], WSCALE_INV, bv), 0.f);
        Obuf[(row + 32) * RS + nb] = q8(v1);
    }
}

// ---------------------------------------------------------------------------
// G3 + coupling, fused. PACKED: MX 16x16x128 (src0 = W_out frag), 4 kb128
// steps, act fragment = 2x ds_read_b128 per kb128 (sigma baked into pack).
// Fallback: old mfma16 path (old layout). Unchanged from R25.
// ---------------------------------------------------------------------------
template<bool PACKED>
__device__ __forceinline__ float gemm16_fused(
    const uchar* __restrict__ wpk,
    const float* __restrict__ wraw,    // raw fp32 W_out [512][64]
    const float* __restrict__ bias,
    const uchar* __restrict__ Abuf,
    float* __restrict__ xbuf,
    const int* __restrict__ ct,        // Ctab row for this layer (64 ints)
    int par, int w, int lane, BPre16 pre)
{
    const int quad = lane >> 4, l15 = lane & 15;
    const int mtb  = w >> 1;           // 0..3
    const int npair = w & 1;
    const int ntb0 = npair, ntb1 = npair + 2;
    const int row  = mtb * 16 + l15;
    v4f acc0, acc1;
    acc0[0] = acc0[1] = acc0[2] = acc0[3] = 0.f;
    acc1[0] = acc1[1] = acc1[2] = acc1[3] = 0.f;

    if constexpr (PACKED) {
        // act k-block C0 = kb*128 + quad*32 -> strip s = kb*4+quad ->
        // low b128 at row*RS + s*16, high at +HHALF
        const uchar* ab = Abuf + row * RS + quad * 16;
        auto loadX = [&](int kb) -> v8i {
            const uchar* p = ab + kb * 64;
            v4i lo = *(const v4i*)p;
            v4i hi = *(const v4i*)(p + HHALF);
            return __builtin_shufflevector(lo, hi, 0, 1, 2, 3, 4, 5, 6, 7);
        };
        const uchar* bw0 = wpk + (size_t)ntb0 * 2048 + (size_t)lane * 32;
        const uchar* bw1 = wpk + (size_t)ntb1 * 2048 + (size_t)lane * 32;

        v8i x0 = loadX(0);
        v8i u0 = pre.u0, v0 = pre.v0;      // kb128 = 0
        v8i u1 = pre.u1, v1 = pre.v1;      // kb128 = 1
        // kb 0
        acc0 = mfma128(u0, x0, acc0);
        acc1 = mfma128(v0, x0, acc1);
        v8i x1 = loadX(1);
        u0 = ldv8(bw0 + 2 * 8192); v0 = ldv8(bw1 + 2 * 8192);
        // kb 1
        acc0 = mfma128(u1, x1, acc0);
        acc1 = mfma128(v1, x1, acc1);
        x0 = loadX(2);
        u1 = ldv8(bw0 + 3 * 8192); v1 = ldv8(bw1 + 3 * 8192);
        // kb 2
        acc0 = mfma128(u0, x0, acc0);
        acc1 = mfma128(v0, x0, acc1);
        x1 = loadX(3);
        // kb 3
        acc0 = mfma128(u1, x1, acc0);
        acc1 = mfma128(v1, x1, acc1);
    } else {
        // fallback: old mfma16 path, pk on the fly (OLD layout)
        const uchar* ap = Abuf + row * RS + (quad & 1) * HHALF + ((quad >> 1) << 3);
        constexpr int KC = 16;
        auto loadB = [&](int ntb, int kc) -> ull {
            if (kc >= KC) kc = KC - 1;
            int n  = ntb * 16 + l15;
            int k0 = kc * 32 + quad * 8;
            unsigned int lo, hi;
            lo = pk2<false>(wraw[(size_t)(k0 + 0) * 64 + n] * WSCALE,
                            wraw[(size_t)(k0 + 1) * 64 + n] * WSCALE, 0u);
            lo = pk2<true >(wraw[(size_t)(k0 + 2) * 64 + n] * WSCALE,
                            wraw[(size_t)(k0 + 3) * 64 + n] * WSCALE, lo);
            hi = pk2<false>(wraw[(size_t)(k0 + 4) * 64 + n] * WSCALE,
                            wraw[(size_t)(k0 + 5) * 64 + n] * WSCALE, 0u);
            hi = pk2<true >(wraw[(size_t)(k0 + 6) * 64 + n] * WSCALE,
                            wraw[(size_t)(k0 + 7) * 64 + n] * WSCALE, hi);
            return ((ull)hi << 32) | (ull)lo;
        };
        auto rdA = [&](int kc) -> ull {
            if (kc >= KC) kc = KC - 1;
            return *(const ull*)(ap + kc * 16);
        };
        ull a0 = rdA(0), a1 = rdA(1), a2 = rdA(2), a3 = rdA(3);
        ull u0 = loadB(ntb0, 0), u1 = loadB(ntb0, 1);
        ull u2 = loadB(ntb0, 2), u3 = loadB(ntb0, 3);
        ull v0 = loadB(ntb1, 0), v1 = loadB(ntb1, 1);
        ull v2 = loadB(ntb1, 2), v3 = loadB(ntb1, 3);
        int kc = 0;
#pragma unroll 1
        for (; kc + 3 < KC; kc += 4) {
            acc0 = mfma16(u0, a0, acc0); acc1 = mfma16(v0, a0, acc1);
            a0 = rdA(kc + 4);
            u0 = loadB(ntb0, kc + 4); v0 = loadB(ntb1, kc + 4);
            acc0 = mfma16(u1, a1, acc0); acc1 = mfma16(v1, a1, acc1);
            a1 = rdA(kc + 5);
            u1 = loadB(ntb0, kc + 5); v1 = loadB(ntb1, kc + 5);
            acc0 = mfma16(u2, a2, acc0); acc1 = mfma16(v2, a2, acc1);
            a2 = rdA(kc + 6);
            u2 = loadB(ntb0, kc + 6); v2 = loadB(ntb1, kc + 6);
            acc0 = mfma16(u3, a3, acc0); acc1 = mfma16(v3, a3, acc1);
            a3 = rdA(kc + 7);
            u3 = loadB(ntb0, kc + 7); v3 = loadB(ntb1, kc + 7);
        }
    }

    // fused coupling epilogue: sc = npair*16 + quad*4 + r (bijective over
    // 0..31 per row across the wave's threads).
    const int n0 = ntb0 * 16 + quad * 4;
    float ld = 0.f;
#pragma unroll
    for (int r = 0; r < 4; ++r) {
        float shiftv = fmaf(acc0[r], WSCALE_INV, bias[n0 + r]);
        float z      = fmaf(acc1[r], WSCALE_INV, bias[32 + n0 + r]) + 2.0f;
        float s      = 1.0f / (1.0f + __expf(-z)) + 0.001f;
        int sc = n0 + r;
        int tc = ct[2 * sc + par];                  // physical column
        float xo = xbuf[row * NF + tc];
        xbuf[row * NF + tc] = xo * s + shiftv;
        ld += __logf(s);
    }
    return ld;
}

template<bool PACKED>
__global__ __launch_bounds__(512, 2) void flow_kernel(
    const float* __restrict__ inputs,
    const float* __restrict__ ctx,
    const float* __restrict__ W_in,  const float* __restrict__ b_in,
    const float* __restrict__ W_h,   const float* __restrict__ b_h,
    const float* __restrict__ W_out, const float* __restrict__ b_out,
    const int*   __restrict__ perms,
    const uchar* __restrict__ wpk,
    float* __restrict__ out)
{
    __shared__ __align__(16) uchar hbuf0[64 * RS];   // 33,792 B
    __shared__ __align__(16) uchar hbuf1[64 * RS];   // 33,792 B
    __shared__ __align__(16) uchar abuf[64 * AST];   // 13,312 B
    __shared__ __align__(16) float xbuf[64 * NF];    // 16,384 B
    __shared__ int Ctab[NL * NF];                    //  2,048 B (~99.3 KB)

    const int tid  = threadIdx.x;     // 0..511
    const int wave = tid >> 6;        // 0..7
    const int lane = tid & 63;
    const int trow = tid >> 3;        // 0..63 (one row per 8 threads)
    const int t8   = tid & 7;         // 0..7
    const int row0 = blockIdx.x * 64;

    // ---- composed perms: Ctab[i][c] = P_0[P_1[...P_{i-1}[c]]]
    {
        int i = tid >> 6, c = tid & 63;     // tid covers all 8*64 entries
        int idx = c;
        for (int k = i - 1; k >= 0; --k) idx = perms[k * NF + idx];
        Ctab[tid] = idx;
    }
    // ---- load + clip x tile (2 float4 per thread)
    {
#pragma unroll
        for (int j = 0; j < 2; ++j) {
            float4 v = ((const float4*)(inputs + (size_t)row0 * NF))[tid + j * 512];
            v.x = fminf(fmaxf(v.x, -1.f), 1.f);
            v.y = fminf(fmaxf(v.y, -1.f), 1.f);
            v.z = fminf(fmaxf(v.z, -1.f), 1.f);
            v.w = fminf(fmaxf(v.w, -1.f), 1.f);
            ((float4*)xbuf)[tid + j * 512] = v;
        }
    }
    // ---- stage ctx ONCE into abuf cols 32..159
    {
        const float* crow = ctx + (size_t)(row0 + trow) * NCTX + t8 * 16;
        float4 f0 = ((const float4*)crow)[0];
        float4 f1 = ((const float4*)crow)[1];
        float4 f2 = ((const float4*)crow)[2];
        float4 f3 = ((const float4*)crow)[3];
        if constexpr (PACKED) {
            // NEW layout: c0 = 32+t8*16; B0 = (1+(t8>>1))*16 + (t8&1)*8
            const int B0 = (1 + (t8 >> 1)) * 16 + (t8 & 1) * 8;
            uint2 r0, r1;
            r0.x = pk2<false>(f0.x, f0.y, 0u);
            r0.x = pk2<true >(f0.z, f0.w, r0.x);
            r0.y = pk2<false>(f2.x, f2.y, 0u);
            r0.y = pk2<true >(f2.z, f2.w, r0.y);
            r1.x = pk2<false>(f1.x, f1.y, 0u);
            r1.x = pk2<true >(f1.z, f1.w, r1.x);
            r1.y = pk2<false>(f3.x, f3.y, 0u);
            r1.y = pk2<true >(f3.z, f3.w, r1.y);
            *(uint2*)(abuf + trow * AST + B0) = r0;
            *(uint2*)(abuf + trow * AST + AHALF + B0) = r1;
        } else {
            // OLD layout
            uint2 ck0, ck1;
            ck0.x = pk2<false>(f0.x, f0.y, 0u);
            ck0.x = pk2<true >(f0.z, f0.w, ck0.x);
            ck0.y = pk2<false>(f1.x, f1.y, 0u);
            ck0.y = pk2<true >(f1.z, f1.w, ck0.y);
            ck1.x = pk2<false>(f2.x, f2.y, 0u);
            ck1.x = pk2<true >(f2.z, f2.w, ck1.x);
            ck1.y = pk2<false>(f3.x, f3.y, 0u);
            ck1.y = pk2<true >(f3.z, f3.w, ck1.y);
            *(uint2*)(abuf + trow * AST + (2 + t8) * 8) = ck0;
            *(uint2*)(abuf + trow * AST + AHALF + (2 + t8) * 8) = ck1;
        }
    }
    // ---- zero-pad abuf cols 160..191 ONCE (A-side of the K=192 pad)
    if constexpr (PACKED) {
        if (tid < 128) {
            int r = tid >> 1, reg = tid & 1;
            v4i z; z[0] = z[1] = z[2] = z[3] = 0;
            *(v4i*)(abuf + r * AST + reg * AHALF + 80) = z;
        }
    } else {
        if (tid < 256) {
            int r = tid >> 2, q = tid & 3;
            *(ull*)(abuf + r * AST + (q & 1) * AHALF + 80 + ((q >> 1) << 3)) = 0ULL;
        }
    }
    float ld_acc = 0.f;

    // ---- prefetch layer-0 G0 B, then barrier (loads ride through)
    BPre preN;
    if constexpr (PACKED) preN = prefB(wpk + OFF_WIN, wave, lane);
    bar_lds();

#pragma unroll 1
    for (int i = 0; i < NL; ++i) {
        const int par = i & 1;
        const int idp = par ^ 1;
        const int* ct = Ctab + i * NF;

        // ---- stage id cols 0..31 into abuf via composed perm
        if (t8 < 4) {
            const float* xr = xbuf + trow * NF;
            if constexpr (PACKED) {
                unsigned int r0, r1;
                r0 = pk2<false>(xr[ct[2 * (t8 * 8 + 0) + idp]],
                                xr[ct[2 * (t8 * 8 + 1) + idp]], 0u);
                r0 = pk2<true >(xr[ct[2 * (t8 * 8 + 2) + idp]],
                                xr[ct[2 * (t8 * 8 + 3) + idp]], r0);
                r1 = pk2<false>(xr[ct[2 * (t8 * 8 + 4) + idp]],
                                xr[ct[2 * (t8 * 8 + 5) + idp]], 0u);
                r1 = pk2<true >(xr[ct[2 * (t8 * 8 + 6) + idp]],
                                xr[ct[2 * (t8 * 8 + 7) + idp]], r1);
                *(unsigned int*)(abuf + trow * AST + t8 * 4) = r0;
                *(unsigned int*)(abuf + trow * AST + AHALF + t8 * 4) = r1;
            } else {
                uint2 idv;
                idv.x = pk2<false>(xr[ct[2 * (t8 * 8 + 0) + idp]],
                                   xr[ct[2 * (t8 * 8 + 1) + idp]], 0u);
                idv.x = pk2<true >(xr[ct[2 * (t8 * 8 + 2) + idp]],
                                   xr[ct[2 * (t8 * 8 + 3) + idp]], idv.x);
                idv.y = pk2<false>(xr[ct[2 * (t8 * 8 + 4) + idp]],
                                   xr[ct[2 * (t8 * 8 + 5) + idp]], 0u);
                idv.y = pk2<true >(xr[ct[2 * (t8 * 8 + 6) + idp]],
                                   xr[ct[2 * (t8 * 8 + 7) + idp]], idv.y);
                *(uint2*)(abuf + trow * AST + (t8 & 1) * AHALF + ((t8 >> 1) << 3)) = idv;
            }
        }
        bar_lds();

        if constexpr (PACKED) {
            const uchar* wg1 = wpk + OFF_WH + (size_t)(i * 2 + 0) * WH_EPB;
            const uchar* wg2 = wpk + OFF_WH + (size_t)(i * 2 + 1) * WH_EPB;
            const uchar* wg3 = wpk + OFF_WOUT + (size_t)i * 32768;
            // ---- G0: K=192 (padded), 3 K-blocks (abuf -> hbuf0)
            gemm32mx<3>(wpk + OFF_WIN + (size_t)i * WIN_EPL, b_in + i * 512,
                        abuf, AST, AHALF, hbuf0, wave, lane, preN);
            BPre pre1 = prefB(wg1, wave, lane);       // G1 B, pre-barrier
            bar_lds();
            // ---- G1 (hbuf0 -> hbuf1), 8 K-blocks
            gemm32mx<8>(wg1, b_h + (i * 2 + 0) * 512,
                        hbuf0, RS, HHALF, hbuf1, wave, lane, pre1);
            BPre pre2 = prefB(wg2, wave, lane);       // G2 B, pre-barrier
            bar_lds();
            // ---- G2 (hbuf1 -> hbuf0)
            gemm32mx<8>(wg2, b_h + (i * 2 + 1) * 512,
                        hbuf1, RS, HHALF, hbuf0, wave, lane, pre2);
            BPre16 pre3 = prefB16(wg3, wave, lane);   // G3 B, pre-barrier
            bar_lds();
            // ---- G3 + coupling fused (hbuf0 -> xbuf update, ld partial)
            ld_acc += gemm16_fused<true>(
                wg3, W_out + (size_t)i * WOUT_EPL, b_out + i * 64,
                hbuf0, xbuf, ct, par, wave, lane, pre3);
            // next layer's G0 B (layer (i+1)&7; last-layer prefetch unused)
            preN = prefB(wpk + OFF_WIN + (size_t)((i + 1) & 7) * WIN_EPL,
                         wave, lane);
            bar_lds();
        } else {
            gemm32_raw<10>(W_in + (size_t)i * (160 * 512), b_in + i * 512,
                           abuf, AST, AHALF, hbuf0, wave * 2 + 0, lane);
            gemm32_raw<10>(W_in + (size_t)i * (160 * 512), b_in + i * 512,
                           abuf, AST, AHALF, hbuf0, wave * 2 + 1, lane);
            bar_lds();
            gemm32_raw<32>(W_h + (size_t)(i * 2 + 0) * WH_EPB,
                           b_h + (i * 2 + 0) * 512,
                           hbuf0, RS, HHALF, hbuf1, wave * 2 + 0, lane);
            gemm32_raw<32>(W_h + (size_t)(i * 2 + 0) * WH_EPB,
                           b_h + (i * 2 + 0) * 512,
                           hbuf0, RS, HHALF, hbuf1, wave * 2 + 1, lane);
            bar_lds();
            gemm32_raw<32>(W_h + (size_t)(i * 2 + 1) * WH_EPB,
                           b_h + (i * 2 + 1) * 512,
                           hbuf1, RS, HHALF, hbuf0, wave * 2 + 0, lane);
            gemm32_raw<32>(W_h + (size_t)(i * 2 + 1) * WH_EPB,
                           b_h + (i * 2 + 1) * 512,
                           hbuf1, RS, HHALF, hbuf0, wave * 2 + 1, lane);
            bar_lds();
            BPre16 dummy{};
            ld_acc += gemm16_fused<false>(
                (const uchar*)0, W_out + (size_t)i * WOUT_EPL, b_out + i * 64,
                hbuf0, xbuf, ct, par, wave, lane, dummy);
            bar_lds();
        }
    }

    // ---- outputs: out[:, c] = clip(x_phys[C_7[c]]) (final gather)
    {
        const int* c7 = Ctab + 7 * NF;
#pragma unroll
        for (int j = 0; j < 2; ++j) {
            int p = tid + j * 512;
            int r = p >> 4, c0 = (p & 15) * 4;
            const float* xr = xbuf + r * NF;
            float4 v;
            v.x = fminf(fmaxf(xr[c7[c0 + 0]], -1.f), 1.f);
            v.y = fminf(fmaxf(xr[c7[c0 + 1]], -1.f), 1.f);
            v.z = fminf(fmaxf(xr[c7[c0 + 2]], -1.f), 1.f);
            v.w = fminf(fmaxf(xr[c7[c0 + 3]], -1.f), 1.f);
            ((float4*)(out + (size_t)row0 * NF))[p] = v;
        }
    }
    // ---- logdet: per-thread partials -> LDS (abuf, dead) -> 8-way reduce
    {
        float* lbuf = (float*)abuf;
        const int rrow = (wave >> 1) * 16 + (lane & 15);
        const int slot = (wave & 1) * 4 + (lane >> 4);
        lbuf[rrow * 8 + slot] = ld_acc;
        bar_lds();
        if (tid < 64) {
            float s = 0.f;
#pragma unroll
            for (int k = 0; k < 8; ++k) s += lbuf[tid * 8 + k];
            out[(size_t)BATCH * NF + row0 + tid] = s;
        }
    }
}

extern "C" void kernel_launch(void* const* d_in, const int* in_sizes, int n_in,
                              void* d_out, int out_size, void* d_ws, size_t ws_size,
                              hipStream_t stream) {
    const float* inputs  = (const float*)d_in[0];
    const float* context = (const float*)d_in[1];
    const float* W_in    = (const float*)d_in[2];
    const float* b_in    = (const float*)d_in[3];
    const float* W_h     = (const float*)d_in[4];
    const float* b_h     = (const float*)d_in[5];
    const float* W_out   = (const float*)d_in[6];
    const float* b_out   = (const float*)d_in[7];
    const int*   perms   = (const int*)d_in[8];
    float* out = (float*)d_out;

    if (ws_size >= (size_t)NEED_WS) {
        uchar* ws = (uchar*)d_ws;
        const int total_threads = NU_TOT * 64;        // 86,016
        pack_weights_kernel<<<(total_threads + 255) / 256, 256, 0, stream>>>(
            W_in, W_h, W_out, ws);
        flow_kernel<true><<<256, 512, 0, stream>>>(
            inputs, context, W_in, b_in, W_h, b_h, W_out, b_out, perms, ws, out);
    } else {
        flow_kernel<false><<<256, 512, 0, stream>>>(
            inputs, context, W_in, b_in, W_h, b_h, W_out, b_out, perms,
            (const uchar*)0, out);
    }
}

// Round 15
// 181.605 us; speedup vs baseline: 1.0359x; 1.0359x over previous
//
#include <hip/hip_runtime.h>

// ---------------------------------------------------------------------------
// MaskedAutoregressiveFlow (RealNVP coupling) fused kernel for gfx950. R28.
// B=16384 rows, F=64, CTX=128, HID=512, L=8 layers, NB=2 hidden blocks.
//
// R28 = R25 RESTORED (best measured: flow 106.2us, total 181.9us).
// R27 post-mortem: inline-asm v_pk_fma_f32 regressed (106->113us) — operand
// marshalling (v_mov pairs into adjacent VGPRs) + asm opacity defeated the
// compiler's fma/max/cvt fusion. VALU lever is net-negative at source level.
// Lever ledger (all counter-evidenced): MX fp8 GEMMs +38%; A-SWP + raw
// barriers + cross-stage B prefetch +12%; write-coalesced LDS (+3%,
// conflicts -45%). Flat/regressed: occupancy both directions, LDS-traffic
// halving, barrier/phase deletion, B depth-4 (spill), packed VALU.
// Remaining gap to the ~37us MFMA floor is the lockstep phase-sum
// structure; breaking it = producer/consumer wave specialization (rewrite).
// C^T mapping (m101, dtype-indep): 32x32: m = lane&31,
// n = (reg&3)+8*(reg>>2)+4*(lane>>5); 16x16: m = lane&15, n = ntb*16+quad*4+reg.
// LDS layout (PACKED): pos(c) = ((c>>2)&1)*HALF + (c>>5)*16 + ((c>>3)&3)*4
// + (c&3); k-order sigma baked into the weight pack (k(g,j) = (g&1)*16 +
// (j>>2)*8 + ((g>>1)&1)*4 + (j&3)).
// ---------------------------------------------------------------------------

typedef float v4f  __attribute__((ext_vector_type(4)));
typedef float v16f __attribute__((ext_vector_type(16)));
typedef int   v4i  __attribute__((ext_vector_type(4)));
typedef int   v8i  __attribute__((ext_vector_type(8)));
typedef unsigned char uchar;
typedef unsigned long long ull;

#define BATCH 16384
#define NF    64
#define NCTX  128
#define NL    8

#define RS     528   // h row stride (bytes)
#define HHALF  256   // byte offset of high half-region (hbuf)
#define AST    208   // abuf row stride (bytes), K padded to 192
#define AHALF  96    // abuf half-region offset (K=192)

#define WSCALE     16.0f
#define WSCALE_INV 0.0625f

// packed-weight offsets (fp8 elements = bytes). W_in K padded 160->192.
#define WIN_EPL   (192 * 512)
#define WH_EPB    (512 * 512)
#define WOUT_EPL  (512 * 64)
#define OFF_WIN   ((size_t)0)
#define OFF_WH    ((size_t)(8 * WIN_EPL))
#define OFF_WOUT  (OFF_WH + (size_t)(16 * WH_EPB))
#define TOT_PACK_ELEMS (OFF_WOUT + (size_t)(8 * WOUT_EPL))
#define NEED_WS   (TOT_PACK_ELEMS)

// pack wave-unit counts
#define NU_IN   192    // 8 layers x 3 kb x 2 khalf x 4 g
#define NU_H    1024   // 16 mats  x 8 kb x 2 khalf x 4 g
#define NU_OUT  128    // 8 layers x 16 kc
#define NU_TOT  (NU_IN + NU_H + NU_OUT)   // 1344 waves

template<bool HI>
__device__ __forceinline__ unsigned int pk2(float a, float b, unsigned int old) {
    return __builtin_amdgcn_cvt_pk_fp8_f32(a, b, old, HI);
}
__device__ __forceinline__ uchar q8(float v) {
    return (uchar)(__builtin_amdgcn_cvt_pk_fp8_f32(v, v, 0u, false) & 0xffu);
}

// Raw barrier: LDS-complete + s_barrier, NO vmcnt drain (global prefetches
// stay in flight). All inter-wave deps in flow_kernel are LDS-only.
__device__ __forceinline__ void bar_lds() {
    asm volatile("s_waitcnt lgkmcnt(0)" ::: "memory");
    __builtin_amdgcn_s_barrier();
    asm volatile("" ::: "memory");
}

// within-32 k base for pack group g: bytes [g*8, g*8+8) of a 32B lane frag
// hold k = kq(g) + (j>>2)*8 + (j&3), kq(g) = (g&1)*16 + ((g>>1)&1)*4.
__device__ __forceinline__ int kqg(int g) {
    return (g & 1) * 16 + ((g >> 1) & 1) * 4;
}

// ---------------------------------------------------------------------------
// pack: wave-per-unit, coalesced reads, register 8x8 transpose.
// W_in/W_h unit (kb,khalf,g): rows k = kb*64 + khalf*32 + kq(g) + (j>>2)*8
// + (j&3), j=0..7; all 512 n. Lane owns n = lane*8..lane*8+7. Dest 8B group
// for n: base + kb*32768 + ((n>>5)*64 + 32*khalf + (n&31))*32 + g*8.
// Units with kb*64+khalf*32 >= rawK (W_in kb=2,khalf=1) write zeros.
// W_out unit (i,kc): lane = n; 32 coalesced row reads; per g(0..3):
// bytes = rows kq(g)+(j>>2)*8+(j&3) of the 32-row slab; dest slot
// l' = ((kc&3)<<4)|(n&15) in block (kc>>2, ntb=n>>4).
// ---------------------------------------------------------------------------
__global__ __launch_bounds__(256) void pack_weights_kernel(
    const float* __restrict__ W_in,
    const float* __restrict__ W_h,
    const float* __restrict__ W_out,
    unsigned char* __restrict__ ws) {
    const int wid  = (blockIdx.x * blockDim.x + threadIdx.x) >> 6;
    const int lane = threadIdx.x & 63;
    if (wid >= NU_TOT) return;

    if (wid < NU_IN + NU_H) {
        const float* src;
        uchar* dstbase;
        int kb, khalf, g, rawK;
        if (wid < NU_IN) {
            int i = wid / 24, r = wid % 24;           // layer, unit-in-layer
            kb = r >> 3; khalf = (r >> 2) & 1; g = r & 3;
            src = W_in + (size_t)i * (160 * 512); rawK = 160;
            dstbase = ws + OFF_WIN + (size_t)i * WIN_EPL + kb * 32768;
        } else {
            int u = wid - NU_IN;
            int ij = u >> 6, r = u & 63;              // matrix, unit-in-matrix
            kb = r >> 3; khalf = (r >> 2) & 1; g = r & 3;
            src = W_h + (size_t)ij * WH_EPB; rawK = 512;
            dstbase = ws + OFF_WH + (size_t)ij * WH_EPB + kb * 32768;
        }
        const int kbase = kb * 64 + khalf * 32;
        const int kq    = kqg(g);
        const int n0    = lane * 8;
        float v[8][8];
        if (kbase < rawK) {
#pragma unroll
            for (int j = 0; j < 8; ++j) {
                const int kj = kbase + kq + (j >> 2) * 8 + (j & 3);
                const float* p = src + (size_t)kj * 512 + n0;
                float4 a = ((const float4*)p)[0];
                float4 b = ((const float4*)p)[1];
                v[j][0] = a.x * WSCALE; v[j][1] = a.y * WSCALE;
                v[j][2] = a.z * WSCALE; v[j][3] = a.w * WSCALE;
                v[j][4] = b.x * WSCALE; v[j][5] = b.y * WSCALE;
                v[j][6] = b.z * WSCALE; v[j][7] = b.w * WSCALE;
            }
        } else {
#pragma unroll
            for (int j = 0; j < 8; ++j)
#pragma unroll
                for (int nn = 0; nn < 8; ++nn) v[j][nn] = 0.f;
        }
        // dest for nn=0; consecutive nn adds 32B
        uchar* dst = dstbase +
            ((lane >> 2) * 64 + 32 * khalf + (lane & 3) * 8) * 32 + g * 8;
#pragma unroll
        for (int nn = 0; nn < 8; ++nn) {
            uint2 o;
            o.x = pk2<false>(v[0][nn], v[1][nn], 0u);
            o.x = pk2<true >(v[2][nn], v[3][nn], o.x);
            o.y = pk2<false>(v[4][nn], v[5][nn], 0u);
            o.y = pk2<true >(v[6][nn], v[7][nn], o.y);
            *(uint2*)(dst + nn * 32) = o;
        }
    } else {
        int u = wid - (NU_IN + NU_H);
        int i = u >> 4, kc = u & 15;                  // layer, kc (32-k slab)
        const int n = lane;
        const float* src = W_out + (size_t)i * WOUT_EPL;
        float v[32];
#pragma unroll
        for (int k = 0; k < 32; ++k)
            v[k] = src[(size_t)(kc * 32 + k) * 64 + n] * WSCALE;
        uchar* dst = ws + OFF_WOUT + (size_t)i * 32768 +
                     (size_t)(kc >> 2) * 8192 + (size_t)(n >> 4) * 2048 +
                     (size_t)((((kc & 3) << 4) | (n & 15)) * 32);
#pragma unroll
        for (int g = 0; g < 4; ++g) {
            const int kq = kqg(g);
            uint2 o;
            o.x = pk2<false>(v[kq + 0], v[kq + 1], 0u);
            o.x = pk2<true >(v[kq + 2], v[kq + 3], o.x);
            o.y = pk2<false>(v[kq + 8], v[kq + 9], 0u);
            o.y = pk2<true >(v[kq + 10], v[kq + 11], o.y);
            *(uint2*)(dst + g * 8) = o;
        }
    }
}

__device__ __forceinline__ v16f mfma32(ull a, ull b, v16f c) {
    return __builtin_amdgcn_mfma_f32_32x32x16_fp8_fp8((long)a, (long)b, c, 0, 0, 0);
}
__device__ __forceinline__ v4f mfma16(ull a, ull b, v4f c) {
    return __builtin_amdgcn_mfma_f32_16x16x32_fp8_fp8((long)a, (long)b, c, 0, 0, 0);
}
// MX, both operands fp8 e4m3 (cbsz=0, blgp=0), scales = 1.0 (E8M0 127).
__device__ __forceinline__ v16f mfma64(v8i a, v8i b, v16f c) {
    return __builtin_amdgcn_mfma_scale_f32_32x32x64_f8f6f4(
        a, b, c, 0, 0, 0, 0x7f7f7f7f, 0, 0x7f7f7f7f);
}
__device__ __forceinline__ v4f mfma128(v8i a, v8i b, v4f c) {
    return __builtin_amdgcn_mfma_scale_f32_16x16x128_f8f6f4(
        a, b, c, 0, 0, 0, 0x7f7f7f7f, 0, 0x7f7f7f7f);
}

__device__ __forceinline__ v8i ldv8(const uchar* p) {
    v4i lo = *(const v4i*)p;
    v4i hi = *(const v4i*)(p + 16);
    return __builtin_shufflevector(lo, hi, 0, 1, 2, 3, 4, 5, 6, 7);
}

// B prefetch payloads (issued before the barrier preceding each stage)
struct BPre  { v8i b00, b10, b01, b11; };             // gemm32mx kb=0,1
struct BPre16 { v8i u0, v0, u1, v1; };                // gemm16 kb128=0,1 x 2 chains

__device__ __forceinline__ BPre prefB(const uchar* __restrict__ wpk,
                                      int pair, int lane) {
    const uchar* bp = wpk + (size_t)(pair * 128 + lane) * 32;
    BPre r;
    r.b00 = ldv8(bp);
    r.b10 = ldv8(bp + 2048);
    r.b01 = ldv8(bp + 32768);
    r.b11 = ldv8(bp + 32768 + 2048);
    return r;
}
__device__ __forceinline__ BPre16 prefB16(const uchar* __restrict__ wpk,
                                          int w, int lane) {
    const int npair = w & 1;
    const uchar* b0 = wpk + (size_t)npair * 2048 + (size_t)lane * 32;
    const uchar* b1 = wpk + (size_t)(npair + 2) * 2048 + (size_t)lane * 32;
    BPre16 r;
    r.u0 = ldv8(b0);        r.v0 = ldv8(b1);
    r.u1 = ldv8(b0 + 8192); r.v1 = ldv8(b1 + 8192);
    return r;
}

// ---------------------------------------------------------------------------
// MX 32x32x64 fp8 stage, 8-wave: wave owns strips {2p, 2p+1} x both m-tiles
// (4 v16f accs). SWAPPED operands (src0 = weight frag, src1 = act frag).
// D=2 B pipeline (kb=0,1 from caller's pre-barrier prefetch), A ping-pong.
// Epilogue: scalar fmaf/fmaxf (compiler fuses best); ONE ds_write_b128 per
// (strip, mhalf) at pos = hl*HHALF + strip*16 — bank-minimal.
// ---------------------------------------------------------------------------
template<int NKB>
__device__ __forceinline__ void gemm32mx(
    const uchar* __restrict__ wpk,
    const float* __restrict__ bias,
    const uchar* __restrict__ Abuf, int ast, int halfoff,
    uchar* __restrict__ Obuf,
    int pair, int lane, BPre pre)
{
    const int l31 = lane & 31, hl = lane >> 5;
    v16f a00, a01, a10, a11;          // acc[strip][mhalf]
#pragma unroll
    for (int r = 0; r < 16; ++r) { a00[r] = 0.f; a01[r] = 0.f;
                                   a10[r] = 0.f; a11[r] = 0.f; }
    const uchar* aLo0 = Abuf + l31 * ast + hl * 16;   // rows 0..31, low region
    const uchar* aHi0 = aLo0 + halfoff;               // high region
    const uchar* aLo1 = aLo0 + 32 * ast;              // rows 32..63
    const uchar* aHi1 = aHi0 + 32 * ast;
    const uchar* bp = wpk + (size_t)(pair * 128 + lane) * 32;  // strip 2p base

    auto loadB = [&](int s, int kb) -> v8i {
        if (kb >= NKB) kb = NKB - 1;                  // clamped dup, in-bounds
        return ldv8(bp + s * 2048 + (size_t)kb * 32768);
    };
    auto loadA = [&](const uchar* lo_, const uchar* hi_, int kb) -> v8i {
        if (kb >= NKB) kb = NKB - 1;                  // clamped dup, in-bounds
        v4i lo = *(const v4i*)(lo_ + kb * 32);
        v4i hi = *(const v4i*)(hi_ + kb * 32);
        return __builtin_shufflevector(lo, hi, 0, 1, 2, 3, 4, 5, 6, 7);
    };

    // prologue: A for kb=0 (slot A) and kb=1 (slot B); B from prefetch
    v8i xA0 = loadA(aLo0, aHi0, 0), xA1 = loadA(aLo1, aHi1, 0);
    v8i xB0 = loadA(aLo0, aHi0, 1), xB1 = loadA(aLo1, aHi1, 1);
    v8i b00 = pre.b00, b10 = pre.b10;
    v8i b01 = pre.b01, b11 = pre.b11;
#pragma unroll 1
    for (int kb = 0; kb + 1 < NKB; kb += 2) {
        // compute kb (slot A), then refill slot A with kb+2
        a00 = mfma64(b00, xA0, a00);
        a01 = mfma64(b00, xA1, a01);
        a10 = mfma64(b10, xA0, a10);
        a11 = mfma64(b10, xA1, a11);
        xA0 = loadA(aLo0, aHi0, kb + 2);
        xA1 = loadA(aLo1, aHi1, kb + 2);
        b00 = loadB(0, kb + 2);
        b10 = loadB(1, kb + 2);
        // compute kb+1 (slot B), then refill slot B with kb+3
        a00 = mfma64(b01, xB0, a00);
        a01 = mfma64(b01, xB1, a01);
        a10 = mfma64(b11, xB0, a10);
        a11 = mfma64(b11, xB1, a11);
        xB0 = loadA(aLo0, aHi0, kb + 3);
        xB1 = loadA(aLo1, aHi1, kb + 3);
        b01 = loadB(0, kb + 3);
        b11 = loadB(1, kb + 3);
    }
    if constexpr (NKB & 1) {                          // tail kb = NKB-1 in slot A
        a00 = mfma64(b00, xA0, a00);
        a01 = mfma64(b00, xA1, a01);
        a10 = mfma64(b10, xA0, a10);
        a11 = mfma64(b10, xA1, a11);
    }

    // epilogue (C^T): lane = batch row m = l31 (mhalf0) / l31+32 (mhalf1);
    // reg-quad q of strip s covers n = s*32 + q*8 + 4*hl + {0..3} -> byte
    // pos (region hl) = s*16 + q*4 + {0..3}: ONE b128 per (strip, mhalf).
    const uchar* ob0 = Obuf + l31 * RS + hl * HHALF;  // mhalf 0
    const uchar* ob1 = ob0 + 32 * RS;                 // mhalf 1
    auto emit = [&](const v16f& am0, const v16f& am1, int strip) {
        v4i w0, w1;
#pragma unroll
        for (int q = 0; q < 4; ++q) {
            const int n0 = strip * 32 + q * 8 + 4 * hl;
            float4 bv = *(const float4*)(bias + n0);
            unsigned int u0, u1;
            u0 = pk2<false>(fmaxf(fmaf(am0[4 * q + 0], WSCALE_INV, bv.x), 0.f),
                            fmaxf(fmaf(am0[4 * q + 1], WSCALE_INV, bv.y), 0.f), 0u);
            u0 = pk2<true >(fmaxf(fmaf(am0[4 * q + 2], WSCALE_INV, bv.z), 0.f),
                            fmaxf(fmaf(am0[4 * q + 3], WSCALE_INV, bv.w), 0.f), u0);
            u1 = pk2<false>(fmaxf(fmaf(am1[4 * q + 0], WSCALE_INV, bv.x), 0.f),
                            fmaxf(fmaf(am1[4 * q + 1], WSCALE_INV, bv.y), 0.f), 0u);
            u1 = pk2<true >(fmaxf(fmaf(am1[4 * q + 2], WSCALE_INV, bv.z), 0.f),
                            fmaxf(fmaf(am1[4 * q + 3], WSCALE_INV, bv.w), 0.f), u1);
            w0[q] = (int)u0;
            w1[q] = (int)u1;
        }
        *(v4i*)(ob0 + strip * 16) = w0;
        *(v4i*)(ob1 + strip * 16) = w1;
    };
    emit(a00, a01, pair * 2 + 0);
    emit(a10, a11, pair * 2 + 1);
}

// ---------------------------------------------------------------------------
// Non-packed fallback: 32x32x16 fp8 stage (pk on the fly, OLD layout:
// pos(c) = ((c>>3)&1)*HALF + (c>>4)*8 + (c&7)) — correctness path only.
// ---------------------------------------------------------------------------
template<int KC>
__device__ __forceinline__ void gemm32_raw(
    const float* __restrict__ wraw,    // raw fp32 [K][512]
    const float* __restrict__ bias,
    const uchar* __restrict__ Abuf, int ast, int ahalf,
    uchar* __restrict__ Obuf,
    int strip, int lane)
{
    constexpr int P = KC / 2;
    const int l31 = lane & 31, hl = lane >> 5;
    v16f acc0, acc1;
#pragma unroll
    for (int r = 0; r < 16; ++r) { acc0[r] = 0.f; acc1[r] = 0.f; }
    const uchar* a0p = Abuf + l31 * ast + hl * ahalf;   // rows 0..31
    const uchar* a1p = a0p + 32 * ast;                  // rows 32..63

    auto loadB = [&](int kc) -> ull {
        if (kc >= KC) kc = KC - 1;
        int n  = strip * 32 + l31;
        int k0 = kc * 16 + hl * 8;
        unsigned int lo, hi;
        lo = pk2<false>(wraw[(size_t)(k0 + 0) * 512 + n] * WSCALE,
                        wraw[(size_t)(k0 + 1) * 512 + n] * WSCALE, 0u);
        lo = pk2<true >(wraw[(size_t)(k0 + 2) * 512 + n] * WSCALE,
                        wraw[(size_t)(k0 + 3) * 512 + n] * WSCALE, lo);
        hi = pk2<false>(wraw[(size_t)(k0 + 4) * 512 + n] * WSCALE,
                        wraw[(size_t)(k0 + 5) * 512 + n] * WSCALE, 0u);
        hi = pk2<true >(wraw[(size_t)(k0 + 6) * 512 + n] * WSCALE,
                        wraw[(size_t)(k0 + 7) * 512 + n] * WSCALE, hi);
        return ((ull)hi << 32) | (ull)lo;
    };

    ull b0 = loadB(0), b1 = loadB(1), b2 = loadB(2), b3 = loadB(3);
    int p2 = 0;
#pragma unroll 1
    for (; p2 + 1 < P; p2 += 2) {
        ulonglong2 Aa0 = *(const ulonglong2*)(a0p + p2 * 16);
        ulonglong2 Aa1 = *(const ulonglong2*)(a1p + p2 * 16);
        acc0 = mfma32(Aa0.x, b0, acc0);
        acc1 = mfma32(Aa1.x, b0, acc1);
        b0 = loadB(2 * p2 + 4);
        acc0 = mfma32(Aa0.y, b1, acc0);
        acc1 = mfma32(Aa1.y, b1, acc1);
        b1 = loadB(2 * p2 + 5);
        ulonglong2 Ab0 = *(const ulonglong2*)(a0p + p2 * 16 + 16);
        ulonglong2 Ab1 = *(const ulonglong2*)(a1p + p2 * 16 + 16);
        acc0 = mfma32(Ab0.x, b2, acc0);
        acc1 = mfma32(Ab1.x, b2, acc1);
        b2 = loadB(2 * p2 + 6);
        acc0 = mfma32(Ab0.y, b3, acc0);
        acc1 = mfma32(Ab1.y, b3, acc1);
        b3 = loadB(2 * p2 + 7);
    }
    if constexpr (P & 1) {
        ulonglong2 Aa0 = *(const ulonglong2*)(a0p + (P - 1) * 16);
        ulonglong2 Aa1 = *(const ulonglong2*)(a1p + (P - 1) * 16);
        acc0 = mfma32(Aa0.x, b0, acc0);
        acc1 = mfma32(Aa1.x, b0, acc1);
        acc0 = mfma32(Aa0.y, b1, acc0);
        acc1 = mfma32(Aa1.y, b1, acc1);
    }

    const int n = strip * 32 + l31;
    const int nb = ((n >> 3) & 1) * HHALF + ((n >> 4) << 3) + (n & 7);
    const float bv = bias[n];
#pragma unroll
    for (int reg = 0; reg < 16; ++reg) {
        int row = (reg & 3) + 8 * (reg >> 2) + 4 * hl;
        float v0 = fmaxf(fmaf(acc0[reg], WSCALE_INV, bv), 0.f);
        Obuf[row * RS + nb] = q8(v0);
        float v1 = fmaxf(fmaf(acc1[reg], WSCALE_INV, bv), 0.f);
        Obuf[(row + 32) * RS + nb] = q8(v1);
    }
}

// ---------------------------------------------------------------------------
// G3 + coupling, fused. PACKED: MX 16x16x128 (src0 = W_out frag), 4 kb128
// steps, act fragment = 2x ds_read_b128 per kb128 (sigma baked into pack).
// Fallback: old mfma16 path (old layout).
// ---------------------------------------------------------------------------
template<bool PACKED>
__device__ __forceinline__ float gemm16_fused(
    const uchar* __restrict__ wpk,
    const float* __restrict__ wraw,    // raw fp32 W_out [512][64]
    const float* __restrict__ bias,
    const uchar* __restrict__ Abuf,
    float* __restrict__ xbuf,
    const int* __restrict__ ct,        // Ctab row for this layer (64 ints)
    int par, int w, int lane, BPre16 pre)
{
    const int quad = lane >> 4, l15 = lane & 15;
    const int mtb  = w >> 1;           // 0..3
    const int npair = w & 1;
    const int ntb0 = npair, ntb1 = npair + 2;
    const int row  = mtb * 16 + l15;
    v4f acc0, acc1;
    acc0[0] = acc0[1] = acc0[2] = acc0[3] = 0.f;
    acc1[0] = acc1[1] = acc1[2] = acc1[3] = 0.f;

    if constexpr (PACKED) {
        // act k-block C0 = kb*128 + quad*32 -> strip s = kb*4+quad ->
        // low b128 at row*RS + s*16, high at +HHALF
        const uchar* ab = Abuf + row * RS + quad * 16;
        auto loadX = [&](int kb) -> v8i {
            const uchar* p = ab + kb * 64;
            v4i lo = *(const v4i*)p;
            v4i hi = *(const v4i*)(p + HHALF);
            return __builtin_shufflevector(lo, hi, 0, 1, 2, 3, 4, 5, 6, 7);
        };
        const uchar* bw0 = wpk + (size_t)ntb0 * 2048 + (size_t)lane * 32;
        const uchar* bw1 = wpk + (size_t)ntb1 * 2048 + (size_t)lane * 32;

        v8i x0 = loadX(0);
        v8i u0 = pre.u0, v0 = pre.v0;      // kb128 = 0
        v8i u1 = pre.u1, v1 = pre.v1;      // kb128 = 1
        // kb 0
        acc0 = mfma128(u0, x0, acc0);
        acc1 = mfma128(v0, x0, acc1);
        v8i x1 = loadX(1);
        u0 = ldv8(bw0 + 2 * 8192); v0 = ldv8(bw1 + 2 * 8192);
        // kb 1
        acc0 = mfma128(u1, x1, acc0);
        acc1 = mfma128(v1, x1, acc1);
        x0 = loadX(2);
        u1 = ldv8(bw0 + 3 * 8192); v1 = ldv8(bw1 + 3 * 8192);
        // kb 2
        acc0 = mfma128(u0, x0, acc0);
        acc1 = mfma128(v0, x0, acc1);
        x1 = loadX(3);
        // kb 3
        acc0 = mfma128(u1, x1, acc0);
        acc1 = mfma128(v1, x1, acc1);
    } else {
        // fallback: old mfma16 path, pk on the fly (OLD layout)
        const uchar* ap = Abuf + row * RS + (quad & 1) * HHALF + ((quad >> 1) << 3);
        constexpr int KC = 16;
        auto loadB = [&](int ntb, int kc) -> ull {
            if (kc >= KC) kc = KC - 1;
            int n  = ntb * 16 + l15;
            int k0 = kc * 32 + quad * 8;
            unsigned int lo, hi;
            lo = pk2<false>(wraw[(size_t)(k0 + 0) * 64 + n] * WSCALE,
                            wraw[(size_t)(k0 + 1) * 64 + n] * WSCALE, 0u);
            lo = pk2<true >(wraw[(size_t)(k0 + 2) * 64 + n] * WSCALE,
                            wraw[(size_t)(k0 + 3) * 64 + n] * WSCALE, lo);
            hi = pk2<false>(wraw[(size_t)(k0 + 4) * 64 + n] * WSCALE,
                            wraw[(size_t)(k0 + 5) * 64 + n] * WSCALE, 0u);
            hi = pk2<true >(wraw[(size_t)(k0 + 6) * 64 + n] * WSCALE,
                            wraw[(size_t)(k0 + 7) * 64 + n] * WSCALE, hi);
            return ((ull)hi << 32) | (ull)lo;
        };
        auto rdA = [&](int kc) -> ull {
            if (kc >= KC) kc = KC - 1;
            return *(const ull*)(ap + kc * 16);
        };
        ull a0 = rdA(0), a1 = rdA(1), a2 = rdA(2), a3 = rdA(3);
        ull u0 = loadB(ntb0, 0), u1 = loadB(ntb0, 1);
        ull u2 = loadB(ntb0, 2), u3 = loadB(ntb0, 3);
        ull v0 = loadB(ntb1, 0), v1 = loadB(ntb1, 1);
        ull v2 = loadB(ntb1, 2), v3 = loadB(ntb1, 3);
        int kc = 0;
#pragma unroll 1
        for (; kc + 3 < KC; kc += 4) {
            acc0 = mfma16(u0, a0, acc0); acc1 = mfma16(v0, a0, acc1);
            a0 = rdA(kc + 4);
            u0 = loadB(ntb0, kc + 4); v0 = loadB(ntb1, kc + 4);
            acc0 = mfma16(u1, a1, acc0); acc1 = mfma16(v1, a1, acc1);
            a1 = rdA(kc + 5);
            u1 = loadB(ntb0, kc + 5); v1 = loadB(ntb1, kc + 5);
            acc0 = mfma16(u2, a2, acc0); acc1 = mfma16(v2, a2, acc1);
            a2 = rdA(kc + 6);
            u2 = loadB(ntb0, kc + 6); v2 = loadB(ntb1, kc + 6);
            acc0 = mfma16(u3, a3, acc0); acc1 = mfma16(v3, a3, acc1);
            a3 = rdA(kc + 7);
            u3 = loadB(ntb0, kc + 7); v3 = loadB(ntb1, kc + 7);
        }
    }

    // fused coupling epilogue: sc = npair*16 + quad*4 + r (bijective over
    // 0..31 per row across the wave's threads).
    const int n0 = ntb0 * 16 + quad * 4;
    float ld = 0.f;
#pragma unroll
    for (int r = 0; r < 4; ++r) {
        float shiftv = fmaf(acc0[r], WSCALE_INV, bias[n0 + r]);
        float z      = fmaf(acc1[r], WSCALE_INV, bias[32 + n0 + r]) + 2.0f;
        float s      = 1.0f / (1.0f + __expf(-z)) + 0.001f;
        int sc = n0 + r;
        int tc = ct[2 * sc + par];                  // physical column
        float xo = xbuf[row * NF + tc];
        xbuf[row * NF + tc] = xo * s + shiftv;
        ld += __logf(s);
    }
    return ld;
}

template<bool PACKED>
__global__ __launch_bounds__(512, 2) void flow_kernel(
    const float* __restrict__ inputs,
    const float* __restrict__ ctx,
    const float* __restrict__ W_in,  const float* __restrict__ b_in,
    const float* __restrict__ W_h,   const float* __restrict__ b_h,
    const float* __restrict__ W_out, const float* __restrict__ b_out,
    const int*   __restrict__ perms,
    const uchar* __restrict__ wpk,
    float* __restrict__ out)
{
    __shared__ __align__(16) uchar hbuf0[64 * RS];   // 33,792 B
    __shared__ __align__(16) uchar hbuf1[64 * RS];   // 33,792 B
    __shared__ __align__(16) uchar abuf[64 * AST];   // 13,312 B
    __shared__ __align__(16) float xbuf[64 * NF];    // 16,384 B
    __shared__ int Ctab[NL * NF];                    //  2,048 B (~99.3 KB)

    const int tid  = threadIdx.x;     // 0..511
    const int wave = tid >> 6;        // 0..7
    const int lane = tid & 63;
    const int trow = tid >> 3;        // 0..63 (one row per 8 threads)
    const int t8   = tid & 7;         // 0..7
    const int row0 = blockIdx.x * 64;

    // ---- composed perms: Ctab[i][c] = P_0[P_1[...P_{i-1}[c]]]
    {
        int i = tid >> 6, c = tid & 63;     // tid covers all 8*64 entries
        int idx = c;
        for (int k = i - 1; k >= 0; --k) idx = perms[k * NF + idx];
        Ctab[tid] = idx;
    }
    // ---- load + clip x tile (2 float4 per thread)
    {
#pragma unroll
        for (int j = 0; j < 2; ++j) {
            float4 v = ((const float4*)(inputs + (size_t)row0 * NF))[tid + j * 512];
            v.x = fminf(fmaxf(v.x, -1.f), 1.f);
            v.y = fminf(fmaxf(v.y, -1.f), 1.f);
            v.z = fminf(fmaxf(v.z, -1.f), 1.f);
            v.w = fminf(fmaxf(v.w, -1.f), 1.f);
            ((float4*)xbuf)[tid + j * 512] = v;
        }
    }
    // ---- stage ctx ONCE into abuf cols 32..159
    {
        const float* crow = ctx + (size_t)(row0 + trow) * NCTX + t8 * 16;
        float4 f0 = ((const float4*)crow)[0];
        float4 f1 = ((const float4*)crow)[1];
        float4 f2 = ((const float4*)crow)[2];
        float4 f3 = ((const float4*)crow)[3];
        if constexpr (PACKED) {
            // NEW layout: c0 = 32+t8*16; B0 = (1+(t8>>1))*16 + (t8&1)*8
            // region0 8B = cols {c0..c0+3, c0+8..c0+11} (f0, f2)
            // region1 8B = cols {c0+4..c0+7, c0+12..c0+15} (f1, f3)
            const int B0 = (1 + (t8 >> 1)) * 16 + (t8 & 1) * 8;
            uint2 r0, r1;
            r0.x = pk2<false>(f0.x, f0.y, 0u);
            r0.x = pk2<true >(f0.z, f0.w, r0.x);
            r0.y = pk2<false>(f2.x, f2.y, 0u);
            r0.y = pk2<true >(f2.z, f2.w, r0.y);
            r1.x = pk2<false>(f1.x, f1.y, 0u);
            r1.x = pk2<true >(f1.z, f1.w, r1.x);
            r1.y = pk2<false>(f3.x, f3.y, 0u);
            r1.y = pk2<true >(f3.z, f3.w, r1.y);
            *(uint2*)(abuf + trow * AST + B0) = r0;
            *(uint2*)(abuf + trow * AST + AHALF + B0) = r1;
        } else {
            // OLD layout
            uint2 ck0, ck1;
            ck0.x = pk2<false>(f0.x, f0.y, 0u);
            ck0.x = pk2<true >(f0.z, f0.w, ck0.x);
            ck0.y = pk2<false>(f1.x, f1.y, 0u);
            ck0.y = pk2<true >(f1.z, f1.w, ck0.y);
            ck1.x = pk2<false>(f2.x, f2.y, 0u);
            ck1.x = pk2<true >(f2.z, f2.w, ck1.x);
            ck1.y = pk2<false>(f3.x, f3.y, 0u);
            ck1.y = pk2<true >(f3.z, f3.w, ck1.y);
            *(uint2*)(abuf + trow * AST + (2 + t8) * 8) = ck0;
            *(uint2*)(abuf + trow * AST + AHALF + (2 + t8) * 8) = ck1;
        }
    }
    // ---- zero-pad abuf cols 160..191 ONCE (A-side of the K=192 pad)
    if constexpr (PACKED) {
        // NEW layout: cols 160..191 -> bytes [80,96) of each region
        if (tid < 128) {
            int r = tid >> 1, reg = tid & 1;
            v4i z; z[0] = z[1] = z[2] = z[3] = 0;
            *(v4i*)(abuf + r * AST + reg * AHALF + 80) = z;
        }
    } else {
        if (tid < 256) {
            int r = tid >> 2, q = tid & 3;
            *(ull*)(abuf + r * AST + (q & 1) * AHALF + 80 + ((q >> 1) << 3)) = 0ULL;
        }
    }
    float ld_acc = 0.f;

    // ---- prefetch layer-0 G0 B, then barrier (loads ride through)
    BPre preN;
    if constexpr (PACKED) preN = prefB(wpk + OFF_WIN, wave, lane);
    bar_lds();

#pragma unroll 1
    for (int i = 0; i < NL; ++i) {
        const int par = i & 1;
        const int idp = par ^ 1;
        const int* ct = Ctab + i * NF;

        // ---- stage id cols 0..31 into abuf via composed perm
        if (t8 < 4) {
            const float* xr = xbuf + trow * NF;
            if constexpr (PACKED) {
                // NEW layout: cols c0=t8*8..+3 -> region0 b32 at t8*4;
                // cols c0+4..+7 -> region1 b32 at t8*4
                unsigned int r0, r1;
                r0 = pk2<false>(xr[ct[2 * (t8 * 8 + 0) + idp]],
                                xr[ct[2 * (t8 * 8 + 1) + idp]], 0u);
                r0 = pk2<true >(xr[ct[2 * (t8 * 8 + 2) + idp]],
                                xr[ct[2 * (t8 * 8 + 3) + idp]], r0);
                r1 = pk2<false>(xr[ct[2 * (t8 * 8 + 4) + idp]],
                                xr[ct[2 * (t8 * 8 + 5) + idp]], 0u);
                r1 = pk2<true >(xr[ct[2 * (t8 * 8 + 6) + idp]],
                                xr[ct[2 * (t8 * 8 + 7) + idp]], r1);
                *(unsigned int*)(abuf + trow * AST + t8 * 4) = r0;
                *(unsigned int*)(abuf + trow * AST + AHALF + t8 * 4) = r1;
            } else {
                uint2 idv;
                idv.x = pk2<false>(xr[ct[2 * (t8 * 8 + 0) + idp]],
                                   xr[ct[2 * (t8 * 8 + 1) + idp]], 0u);
                idv.x = pk2<true >(xr[ct[2 * (t8 * 8 + 2) + idp]],
                                   xr[ct[2 * (t8 * 8 + 3) + idp]], idv.x);
                idv.y = pk2<false>(xr[ct[2 * (t8 * 8 + 4) + idp]],
                                   xr[ct[2 * (t8 * 8 + 5) + idp]], 0u);
                idv.y = pk2<true >(xr[ct[2 * (t8 * 8 + 6) + idp]],
                                   xr[ct[2 * (t8 * 8 + 7) + idp]], idv.y);
                *(uint2*)(abuf + trow * AST + (t8 & 1) * AHALF + ((t8 >> 1) << 3)) = idv;
            }
        }
        bar_lds();

        if constexpr (PACKED) {
            const uchar* wg1 = wpk + OFF_WH + (size_t)(i * 2 + 0) * WH_EPB;
            const uchar* wg2 = wpk + OFF_WH + (size_t)(i * 2 + 1) * WH_EPB;
            const uchar* wg3 = wpk + OFF_WOUT + (size_t)i * 32768;
            // ---- G0: K=192 (padded), 3 K-blocks (abuf -> hbuf0)
            gemm32mx<3>(wpk + OFF_WIN + (size_t)i * WIN_EPL, b_in + i * 512,
                        abuf, AST, AHALF, hbuf0, wave, lane, preN);
            BPre pre1 = prefB(wg1, wave, lane);       // G1 B, pre-barrier
            bar_lds();
            // ---- G1 (hbuf0 -> hbuf1), 8 K-blocks
            gemm32mx<8>(wg1, b_h + (i * 2 + 0) * 512,
                        hbuf0, RS, HHALF, hbuf1, wave, lane, pre1);
            BPre pre2 = prefB(wg2, wave, lane);       // G2 B, pre-barrier
            bar_lds();
            // ---- G2 (hbuf1 -> hbuf0)
            gemm32mx<8>(wg2, b_h + (i * 2 + 1) * 512,
                        hbuf1, RS, HHALF, hbuf0, wave, lane, pre2);
            BPre16 pre3 = prefB16(wg3, wave, lane);   // G3 B, pre-barrier
            bar_lds();
            // ---- G3 + coupling fused (hbuf0 -> xbuf update, ld partial)
            ld_acc += gemm16_fused<true>(
                wg3, W_out + (size_t)i * WOUT_EPL, b_out + i * 64,
                hbuf0, xbuf, ct, par, wave, lane, pre3);
            // next layer's G0 B (layer (i+1)&7; last-layer prefetch unused)
            preN = prefB(wpk + OFF_WIN + (size_t)((i + 1) & 7) * WIN_EPL,
                         wave, lane);
            bar_lds();
        } else {
            gemm32_raw<10>(W_in + (size_t)i * (160 * 512), b_in + i * 512,
                           abuf, AST, AHALF, hbuf0, wave * 2 + 0, lane);
            gemm32_raw<10>(W_in + (size_t)i * (160 * 512), b_in + i * 512,
                           abuf, AST, AHALF, hbuf0, wave * 2 + 1, lane);
            bar_lds();
            gemm32_raw<32>(W_h + (size_t)(i * 2 + 0) * WH_EPB,
                           b_h + (i * 2 + 0) * 512,
                           hbuf0, RS, HHALF, hbuf1, wave * 2 + 0, lane);
            gemm32_raw<32>(W_h + (size_t)(i * 2 + 0) * WH_EPB,
                           b_h + (i * 2 + 0) * 512,
                           hbuf0, RS, HHALF, hbuf1, wave * 2 + 1, lane);
            bar_lds();
            gemm32_raw<32>(W_h + (size_t)(i * 2 + 1) * WH_EPB,
                           b_h + (i * 2 + 1) * 512,
                           hbuf1, RS, HHALF, hbuf0, wave * 2 + 0, lane);
            gemm32_raw<32>(W_h + (size_t)(i * 2 + 1) * WH_EPB,
                           b_h + (i * 2 + 1) * 512,
                           hbuf1, RS, HHALF, hbuf0, wave * 2 + 1, lane);
            bar_lds();
            BPre16 dummy{};
            ld_acc += gemm16_fused<false>(
                (const uchar*)0, W_out + (size_t)i * WOUT_EPL, b_out + i * 64,
                hbuf0, xbuf, ct, par, wave, lane, dummy);
            bar_lds();
        }
    }

    // ---- outputs: out[:, c] = clip(x_phys[C_7[c]]) (final gather)
    {
        const int* c7 = Ctab + 7 * NF;
#pragma unroll
        for (int j = 0; j < 2; ++j) {
            int p = tid + j * 512;
            int r = p >> 4, c0 = (p & 15) * 4;
            const float* xr = xbuf + r * NF;
            float4 v;
            v.x = fminf(fmaxf(xr[c7[c0 + 0]], -1.f), 1.f);
            v.y = fminf(fmaxf(xr[c7[c0 + 1]], -1.f), 1.f);
            v.z = fminf(fmaxf(xr[c7[c0 + 2]], -1.f), 1.f);
            v.w = fminf(fmaxf(xr[c7[c0 + 3]], -1.f), 1.f);
            ((float4*)(out + (size_t)row0 * NF))[p] = v;
        }
    }
    // ---- logdet: per-thread partials -> LDS (abuf, dead) -> 8-way reduce
    {
        float* lbuf = (float*)abuf;
        const int rrow = (wave >> 1) * 16 + (lane & 15);
        const int slot = (wave & 1) * 4 + (lane >> 4);
        lbuf[rrow * 8 + slot] = ld_acc;
        bar_lds();
        if (tid < 64) {
            float s = 0.f;
#pragma unroll
            for (int k = 0; k < 8; ++k) s += lbuf[tid * 8 + k];
            out[(size_t)BATCH * NF + row0 + tid] = s;
        }
    }
}

extern "C" void kernel_launch(void* const* d_in, const int* in_sizes, int n_in,
                              void* d_out, int out_size, void* d_ws, size_t ws_size,
                              hipStream_t stream) {
    const float* inputs  = (const float*)d_in[0];
    const float* context = (const float*)d_in[1];
    const float* W_in    = (const float*)d_in[2];
    const float* b_in    = (const float*)d_in[3];
    const float* W_h     = (const float*)d_in[4];
    const float* b_h     = (const float*)d_in[5];
    const float* W_out   = (const float*)d_in[6];
    const float* b_out   = (const float*)d_in[7];
    const int*   perms   = (const int*)d_in[8];
    float* out = (float*)d_out;

    if (ws_size >= (size_t)NEED_WS) {
        uchar* ws = (uchar*)d_ws;
        const int total_threads = NU_TOT * 64;        // 86,016
        pack_weights_kernel<<<(total_threads + 255) / 256, 256, 0, stream>>>(
            W_in, W_h, W_out, ws);
        flow_kernel<true><<<256, 512, 0, stream>>>(
            inputs, context, W_in, b_in, W_h, b_h, W_out, b_out, perms, ws, out);
    } else {
        flow_kernel<false><<<256, 512, 0, stream>>>(
            inputs, context, W_in, b_in, W_h, b_h, W_out, b_out, perms,
            (const uchar*)0, out);
    }
}